// Round 2
// baseline (10692.691 us; speedup 1.0000x reference)
//
#include <hip/hip_runtime.h>
#include <math.h>

#define N_NODES 128000
#define B_G 256
#define NPG 500
#define F_IN 128
#define D_LAT 32
#define K_TOP 30
#define L_LAYERS 3
#define E_EDGES 2048000

// ---------------------------------------------------------------------------
// Kernel 1: ego = relu(X @ w0a + b0a) @ w0b + b0b ;  out = alpha[0] * ego
// 64 rows per block, 256 threads: thread = (row-group rg=t>>5, channel d=t&31)
// ---------------------------------------------------------------------------
__global__ __launch_bounds__(256) void k_mlp0(
    const float* __restrict__ X, const float* __restrict__ w0a,
    const float* __restrict__ b0a, const float* __restrict__ w0b,
    const float* __restrict__ b0b, const float* __restrict__ alpha,
    float* __restrict__ ego, float* __restrict__ outb)
{
    __shared__ float sW0a[F_IN * D_LAT];   // 16 KB
    __shared__ float sW0b[D_LAT * D_LAT];  // 4 KB
    __shared__ float sB[2][D_LAT];
    __shared__ float sX[64 * F_IN];        // 32 KB
    __shared__ float sH[64 * 33];          // 8.25 KB (pad 33: conflict-free)

    const int t = threadIdx.x;
    const int blk = blockIdx.x;

    {   // stage weights (contiguous -> float4 coalesced)
        const float4* s1 = (const float4*)w0a;  float4* d1 = (float4*)sW0a;
        for (int i = t; i < F_IN * D_LAT / 4; i += 256) d1[i] = s1[i];
        const float4* s2 = (const float4*)w0b;  float4* d2 = (float4*)sW0b;
        for (int i = t; i < D_LAT * D_LAT / 4; i += 256) d2[i] = s2[i];
        if (t < D_LAT) { sB[0][t] = b0a[t]; sB[1][t] = b0b[t]; }
    }
    {   // stage X tile: 64 rows x 128 = one contiguous 32 KB chunk
        const float4* s = (const float4*)(X + (size_t)blk * 64 * F_IN);
        float4* d = (float4*)sX;
        for (int i = t; i < 64 * F_IN / 4; i += 256) d[i] = s[i];
    }
    __syncthreads();

    const int d = t & 31;
    const int rg = t >> 5;     // 0..7, each handles 8 rows
    const float a0 = alpha[0];

    for (int rr = 0; rr < 8; ++rr) {
        const int r = rg * 8 + rr;
        float acc = sB[0][d];
        #pragma unroll 8
        for (int f = 0; f < F_IN; ++f)
            acc = fmaf(sX[r * F_IN + f], sW0a[f * D_LAT + d], acc);
        sH[r * 33 + d] = fmaxf(acc, 0.f);
    }
    __syncthreads();
    for (int rr = 0; rr < 8; ++rr) {
        const int r = rg * 8 + rr;
        float acc = sB[1][d];
        #pragma unroll
        for (int dd = 0; dd < D_LAT; ++dd)
            acc = fmaf(sH[r * 33 + dd], sW0b[dd * D_LAT + d], acc);
        const size_t gi = ((size_t)blk * 64 + r) * D_LAT + d;
        ego[gi] = acc;
        outb[gi] = a0 * acc;
    }
}

// ---------------------------------------------------------------------------
// Kernel 2: neig[dst] += ego[src]  (scatter-add over edges)
// thread = (edge, 16-channel half): float4 gather + 16 scalar f32 atomics
// ---------------------------------------------------------------------------
__global__ __launch_bounds__(256) void k_scatter(
    const float* __restrict__ ego, const int* __restrict__ esrc,
    const int* __restrict__ edst, float* __restrict__ neig)
{
    const int tid = blockIdx.x * 256 + threadIdx.x;
    const int e = tid >> 1;
    if (e >= E_EDGES) return;
    const int half = (tid & 1) << 4;   // 0 or 16
    const int s  = esrc[e];
    const int dn = edst[e];
    const float4* sp = (const float4*)(ego + (size_t)s * D_LAT + half);
    const float4 v0 = sp[0], v1 = sp[1], v2 = sp[2], v3 = sp[3];
    float* dp = neig + (size_t)dn * D_LAT + half;
    atomicAdd(dp + 0,  v0.x); atomicAdd(dp + 1,  v0.y);
    atomicAdd(dp + 2,  v0.z); atomicAdd(dp + 3,  v0.w);
    atomicAdd(dp + 4,  v1.x); atomicAdd(dp + 5,  v1.y);
    atomicAdd(dp + 6,  v1.z); atomicAdd(dp + 7,  v1.w);
    atomicAdd(dp + 8,  v2.x); atomicAdd(dp + 9,  v2.y);
    atomicAdd(dp + 10, v2.z); atomicAdd(dp + 11, v2.w);
    atomicAdd(dp + 12, v3.x); atomicAdd(dp + 13, v3.y);
    atomicAdd(dp + 14, v3.z); atomicAdd(dp + 15, v3.w);
}

// ---------------------------------------------------------------------------
// Kernel 3: per-layer combine.
// concat([ego,neig,neig+ego]) @ W1a  ==  ego@(Wa0+Wa2) + neig@(Wa1+Wa2)
// hidden = relu(... + B1a); ego' = hidden @ W1b + B1b; out += alpha_l * ego'
// ---------------------------------------------------------------------------
__global__ __launch_bounds__(256) void k_mlp1(
    const float* __restrict__ ego_in, const float* __restrict__ neig,
    const float* __restrict__ W1a_l, const float* __restrict__ B1a_l,
    const float* __restrict__ W1b_l, const float* __restrict__ B1b_l,
    const float* __restrict__ alpha, const int l,
    float* __restrict__ ego_out, float* __restrict__ outb)
{
    __shared__ float sWe[32 * 32], sWn[32 * 32], sWb[32 * 32];
    __shared__ float sB[2][32];
    __shared__ float sE[64 * 32], sNg[64 * 32];
    __shared__ float sH[64 * 33];

    const int t = threadIdx.x;
    const int blk = blockIdx.x;

    for (int i = t; i < 1024; i += 256) {
        const float wc = W1a_l[2048 + i];          // rows 64..95 (neig+ego part)
        sWe[i] = W1a_l[i] + wc;                    // rows 0..31  + combined
        sWn[i] = W1a_l[1024 + i] + wc;             // rows 32..63 + combined
        sWb[i] = W1b_l[i];
    }
    if (t < 32) { sB[0][t] = B1a_l[t]; sB[1][t] = B1b_l[t]; }
    {
        const float4* se = (const float4*)(ego_in + (size_t)blk * 64 * 32);
        const float4* sn = (const float4*)(neig  + (size_t)blk * 64 * 32);
        float4* de = (float4*)sE; float4* dn4 = (float4*)sNg;
        for (int i = t; i < 512; i += 256) { de[i] = se[i]; dn4[i] = sn[i]; }
    }
    __syncthreads();

    const int d = t & 31;
    const int rg = t >> 5;
    const float al = alpha[l + 1];

    for (int rr = 0; rr < 8; ++rr) {
        const int r = rg * 8 + rr;
        float acc = sB[0][d];
        #pragma unroll
        for (int dd = 0; dd < 32; ++dd)
            acc = fmaf(sE[r * 32 + dd], sWe[dd * 32 + d],
                       fmaf(sNg[r * 32 + dd], sWn[dd * 32 + d], acc));
        sH[r * 33 + d] = fmaxf(acc, 0.f);
    }
    __syncthreads();
    for (int rr = 0; rr < 8; ++rr) {
        const int r = rg * 8 + rr;
        float acc = sB[1][d];
        #pragma unroll
        for (int dd = 0; dd < 32; ++dd)
            acc = fmaf(sH[r * 33 + dd], sWb[dd * 32 + d], acc);
        const size_t gi = ((size_t)blk * 64 + r) * 32 + d;
        ego_out[gi] = acc;                 // in-place safe: tile staged pre-sync
        outb[gi] += al * acc;
    }
}

// ---------------------------------------------------------------------------
// Kernel 4: per-graph top-30 on ego[:,31] (stable: ties -> smaller index),
// then gather out rows + relu into d_out. One block per graph.
// ---------------------------------------------------------------------------
__global__ __launch_bounds__(256) void k_topk(
    const float* __restrict__ ego, const float* __restrict__ outb,
    float* __restrict__ y)
{
    __shared__ float vals[512];
    __shared__ int topidx[K_TOP];
    __shared__ float wv[4];
    __shared__ int wi[4];

    const int g = blockIdx.x, t = threadIdx.x;
    for (int i = t; i < 512; i += 256)
        vals[i] = (i < NPG) ? ego[((size_t)g * NPG + i) * D_LAT + (D_LAT - 1)]
                            : -INFINITY;
    __syncthreads();

    for (int k = 0; k < K_TOP; ++k) {
        float v = -INFINITY; int bi = 0x7fffffff;
        for (int i = t; i < NPG; i += 256) {
            const float x = vals[i];
            if (x > v || (x == v && i < bi)) { v = x; bi = i; }
        }
        for (int off = 32; off > 0; off >>= 1) {
            const float ov = __shfl_down(v, off);
            const int   oi = __shfl_down(bi, off);
            if (ov > v || (ov == v && oi < bi)) { v = ov; bi = oi; }
        }
        if ((t & 63) == 0) { wv[t >> 6] = v; wi[t >> 6] = bi; }
        __syncthreads();
        if (t == 0) {
            for (int w = 1; w < 4; ++w)
                if (wv[w] > v || (wv[w] == v && wi[w] < bi)) { v = wv[w]; bi = wi[w]; }
            topidx[k] = bi;
            vals[bi] = -INFINITY;
        }
        __syncthreads();
    }

    for (int j = t; j < K_TOP * D_LAT; j += 256) {
        const int kk = j >> 5, d = j & 31;
        const size_t node = (size_t)g * NPG + topidx[kk];
        y[(size_t)g * (K_TOP * D_LAT) + j] = fmaxf(outb[node * D_LAT + d], 0.f);
    }
}

// ---------------------------------------------------------------------------
extern "C" void kernel_launch(void* const* d_in, const int* in_sizes, int n_in,
                              void* d_out, int out_size, void* d_ws, size_t ws_size,
                              hipStream_t stream)
{
    const float* X    = (const float*)d_in[0];
    const float* alpha= (const float*)d_in[1];
    const float* w0a  = (const float*)d_in[2];
    const float* b0a  = (const float*)d_in[3];
    const float* w0b  = (const float*)d_in[4];
    const float* b0b  = (const float*)d_in[5];
    const float* W1a  = (const float*)d_in[6];
    const float* B1a  = (const float*)d_in[7];
    const float* W1b  = (const float*)d_in[8];
    const float* B1b  = (const float*)d_in[9];
    const int* esrc   = (const int*)d_in[10];
    const int* edst   = (const int*)d_in[11];
    float* y = (float*)d_out;

    float* ego  = (float*)d_ws;
    float* outb = ego  + (size_t)N_NODES * D_LAT;
    float* neig = outb + (size_t)N_NODES * D_LAT;

    k_mlp0<<<N_NODES / 64, 256, 0, stream>>>(X, w0a, b0a, w0b, b0b, alpha, ego, outb);

    for (int l = 0; l < L_LAYERS; ++l) {
        hipMemsetAsync(neig, 0, (size_t)N_NODES * D_LAT * sizeof(float), stream);
        k_scatter<<<(E_EDGES * 2) / 256, 256, 0, stream>>>(ego, esrc, edst, neig);
        k_mlp1<<<N_NODES / 64, 256, 0, stream>>>(
            ego, neig, W1a + (size_t)l * 96 * 32, B1a + (size_t)l * 32,
            W1b + (size_t)l * 32 * 32, B1b + (size_t)l * 32, alpha, l, ego, outb);
    }

    k_topk<<<B_G, 256, 0, stream>>>(ego, outb, y);
}

// Round 3
// 781.285 us; speedup vs baseline: 13.6860x; 13.6860x over previous
//
#include <hip/hip_runtime.h>
#include <math.h>

#define N_NODES 128000
#define B_G 256
#define NPG 500
#define F_IN 128
#define D_LAT 32
#define K_TOP 30
#define L_LAYERS 3
#define E_EDGES 2048000

// ---------------------------------------------------------------------------
// Kernel 1: ego = relu(X @ w0a + b0a) @ w0b + b0b ;  out = alpha[0] * ego
// ---------------------------------------------------------------------------
__global__ __launch_bounds__(256) void k_mlp0(
    const float* __restrict__ X, const float* __restrict__ w0a,
    const float* __restrict__ b0a, const float* __restrict__ w0b,
    const float* __restrict__ b0b, const float* __restrict__ alpha,
    float* __restrict__ ego, float* __restrict__ outb)
{
    __shared__ float sW0a[F_IN * D_LAT];   // 16 KB
    __shared__ float sW0b[D_LAT * D_LAT];  // 4 KB
    __shared__ float sB[2][D_LAT];
    __shared__ float sX[64 * F_IN];        // 32 KB
    __shared__ float sH[64 * 33];          // pad 33: conflict-free

    const int t = threadIdx.x;
    const int blk = blockIdx.x;

    {
        const float4* s1 = (const float4*)w0a;  float4* d1 = (float4*)sW0a;
        for (int i = t; i < F_IN * D_LAT / 4; i += 256) d1[i] = s1[i];
        const float4* s2 = (const float4*)w0b;  float4* d2 = (float4*)sW0b;
        for (int i = t; i < D_LAT * D_LAT / 4; i += 256) d2[i] = s2[i];
        if (t < D_LAT) { sB[0][t] = b0a[t]; sB[1][t] = b0b[t]; }
    }
    {
        const float4* s = (const float4*)(X + (size_t)blk * 64 * F_IN);
        float4* d = (float4*)sX;
        for (int i = t; i < 64 * F_IN / 4; i += 256) d[i] = s[i];
    }
    __syncthreads();

    const int d = t & 31;
    const int rg = t >> 5;
    const float a0 = alpha[0];

    for (int rr = 0; rr < 8; ++rr) {
        const int r = rg * 8 + rr;
        float acc = sB[0][d];
        #pragma unroll 8
        for (int f = 0; f < F_IN; ++f)
            acc = fmaf(sX[r * F_IN + f], sW0a[f * D_LAT + d], acc);
        sH[r * 33 + d] = fmaxf(acc, 0.f);
    }
    __syncthreads();
    for (int rr = 0; rr < 8; ++rr) {
        const int r = rg * 8 + rr;
        float acc = sB[1][d];
        #pragma unroll
        for (int dd = 0; dd < D_LAT; ++dd)
            acc = fmaf(sH[r * 33 + dd], sW0b[dd * D_LAT + d], acc);
        const size_t gi = ((size_t)blk * 64 + r) * D_LAT + d;
        ego[gi] = acc;
        outb[gi] = a0 * acc;
    }
}

// ---------------------------------------------------------------------------
// CSR build: histogram -> exclusive scan (3-level) -> bucket fill
// off[] doubles as the count array (in-place scan is safe: each scan1 block
// reads its 512 range once before writing it).
// ---------------------------------------------------------------------------
__global__ __launch_bounds__(256) void k_hist(
    const int* __restrict__ edst, int* __restrict__ off)
{
    const int e = blockIdx.x * 256 + threadIdx.x;
    if (e < E_EDGES) atomicAdd(&off[edst[e]], 1);
}

__global__ __launch_bounds__(512) void k_scan1(
    int* __restrict__ off, int* __restrict__ part)
{
    __shared__ int buf[2][512];
    const int t = threadIdx.x, b = blockIdx.x;
    const int g = b * 512 + t;
    const int v = (g < N_NODES) ? off[g] : 0;
    buf[0][t] = v;
    __syncthreads();
    int cur = 0;
    for (int o = 1; o < 512; o <<= 1) {
        int x = buf[cur][t];
        if (t >= o) x += buf[cur][t - o];
        buf[cur ^ 1][t] = x;
        cur ^= 1;
        __syncthreads();
    }
    if (g < N_NODES) off[g] = buf[cur][t] - v;   // block-local exclusive
    if (t == 511) part[b] = buf[cur][511];        // block sum
}

__global__ __launch_bounds__(256) void k_scan2(int* __restrict__ part, int nb)
{
    __shared__ int buf[2][256];
    const int t = threadIdx.x;
    const int v = (t < nb) ? part[t] : 0;
    buf[0][t] = v;
    __syncthreads();
    int cur = 0;
    for (int o = 1; o < 256; o <<= 1) {
        int x = buf[cur][t];
        if (t >= o) x += buf[cur][t - o];
        buf[cur ^ 1][t] = x;
        cur ^= 1;
        __syncthreads();
    }
    if (t < nb) part[t] = buf[cur][t] - v;        // exclusive
}

__global__ __launch_bounds__(512) void k_scan3(
    int* __restrict__ off, const int* __restrict__ part, int* __restrict__ cursor)
{
    const int b = blockIdx.x, t = threadIdx.x;
    const int g = b * 512 + t;
    if (g < N_NODES) {
        const int o = off[g] + part[b];
        off[g] = o;
        cursor[g] = o;
    }
    if (g == 0) off[N_NODES] = E_EDGES;
}

__global__ __launch_bounds__(256) void k_fill(
    const int* __restrict__ esrc, const int* __restrict__ edst,
    int* __restrict__ cursor, int* __restrict__ srcidx)
{
    const int e = blockIdx.x * 256 + threadIdx.x;
    if (e < E_EDGES) {
        const int pos = atomicAdd(&cursor[edst[e]], 1);
        srcidx[pos] = esrc[e];
    }
}

// ---------------------------------------------------------------------------
// Atomic-free SpMM gather: neig[n,:] = sum_{i in bucket(n)} ego[srcidx[i],:]
// 8 lanes x float4 per node, 32 nodes per 256-thread block.
// ---------------------------------------------------------------------------
__global__ __launch_bounds__(256) void k_gather(
    const float* __restrict__ ego, const int* __restrict__ off,
    const int* __restrict__ srcidx, float* __restrict__ neig)
{
    const int t = threadIdx.x;
    const int node = blockIdx.x * 32 + (t >> 3);
    const int c = (t & 7) * 4;
    const int s0 = off[node], s1 = off[node + 1];
    float4 acc = {0.f, 0.f, 0.f, 0.f};
    for (int i = s0; i < s1; ++i) {
        const int s = srcidx[i];
        const float4 v = *(const float4*)(ego + (size_t)s * D_LAT + c);
        acc.x += v.x; acc.y += v.y; acc.z += v.z; acc.w += v.w;
    }
    *(float4*)(neig + (size_t)node * D_LAT + c) = acc;
}

// ---------------------------------------------------------------------------
// Per-layer combine (concat folded algebraically)
// ---------------------------------------------------------------------------
__global__ __launch_bounds__(256) void k_mlp1(
    const float* __restrict__ ego_in, const float* __restrict__ neig,
    const float* __restrict__ W1a_l, const float* __restrict__ B1a_l,
    const float* __restrict__ W1b_l, const float* __restrict__ B1b_l,
    const float* __restrict__ alpha, const int l,
    float* __restrict__ ego_out, float* __restrict__ outb)
{
    __shared__ float sWe[32 * 32], sWn[32 * 32], sWb[32 * 32];
    __shared__ float sB[2][32];
    __shared__ float sE[64 * 32], sNg[64 * 32];
    __shared__ float sH[64 * 33];

    const int t = threadIdx.x;
    const int blk = blockIdx.x;

    for (int i = t; i < 1024; i += 256) {
        const float wc = W1a_l[2048 + i];
        sWe[i] = W1a_l[i] + wc;
        sWn[i] = W1a_l[1024 + i] + wc;
        sWb[i] = W1b_l[i];
    }
    if (t < 32) { sB[0][t] = B1a_l[t]; sB[1][t] = B1b_l[t]; }
    {
        const float4* se = (const float4*)(ego_in + (size_t)blk * 64 * 32);
        const float4* sn = (const float4*)(neig  + (size_t)blk * 64 * 32);
        float4* de = (float4*)sE; float4* dn4 = (float4*)sNg;
        for (int i = t; i < 512; i += 256) { de[i] = se[i]; dn4[i] = sn[i]; }
    }
    __syncthreads();

    const int d = t & 31;
    const int rg = t >> 5;
    const float al = alpha[l + 1];

    for (int rr = 0; rr < 8; ++rr) {
        const int r = rg * 8 + rr;
        float acc = sB[0][d];
        #pragma unroll
        for (int dd = 0; dd < 32; ++dd)
            acc = fmaf(sE[r * 32 + dd], sWe[dd * 32 + d],
                       fmaf(sNg[r * 32 + dd], sWn[dd * 32 + d], acc));
        sH[r * 33 + d] = fmaxf(acc, 0.f);
    }
    __syncthreads();
    for (int rr = 0; rr < 8; ++rr) {
        const int r = rg * 8 + rr;
        float acc = sB[1][d];
        #pragma unroll
        for (int dd = 0; dd < 32; ++dd)
            acc = fmaf(sH[r * 33 + dd], sWb[dd * 32 + d], acc);
        const size_t gi = ((size_t)blk * 64 + r) * 32 + d;
        ego_out[gi] = acc;
        outb[gi] += al * acc;
    }
}

// ---------------------------------------------------------------------------
// Per-graph top-30 on ego[:,31] (stable ties -> smaller index) + gather + relu
// ---------------------------------------------------------------------------
__global__ __launch_bounds__(256) void k_topk(
    const float* __restrict__ ego, const float* __restrict__ outb,
    float* __restrict__ y)
{
    __shared__ float vals[512];
    __shared__ int topidx[K_TOP];
    __shared__ float wv[4];
    __shared__ int wi[4];

    const int g = blockIdx.x, t = threadIdx.x;
    for (int i = t; i < 512; i += 256)
        vals[i] = (i < NPG) ? ego[((size_t)g * NPG + i) * D_LAT + (D_LAT - 1)]
                            : -INFINITY;
    __syncthreads();

    for (int k = 0; k < K_TOP; ++k) {
        float v = -INFINITY; int bi = 0x7fffffff;
        for (int i = t; i < NPG; i += 256) {
            const float x = vals[i];
            if (x > v || (x == v && i < bi)) { v = x; bi = i; }
        }
        for (int off = 32; off > 0; off >>= 1) {
            const float ov = __shfl_down(v, off);
            const int   oi = __shfl_down(bi, off);
            if (ov > v || (ov == v && oi < bi)) { v = ov; bi = oi; }
        }
        if ((t & 63) == 0) { wv[t >> 6] = v; wi[t >> 6] = bi; }
        __syncthreads();
        if (t == 0) {
            for (int w = 1; w < 4; ++w)
                if (wv[w] > v || (wv[w] == v && wi[w] < bi)) { v = wv[w]; bi = wi[w]; }
            topidx[k] = bi;
            vals[bi] = -INFINITY;
        }
        __syncthreads();
    }

    for (int j = t; j < K_TOP * D_LAT; j += 256) {
        const int kk = j >> 5, d = j & 31;
        const size_t node = (size_t)g * NPG + topidx[kk];
        y[(size_t)g * (K_TOP * D_LAT) + j] = fmaxf(outb[node * D_LAT + d], 0.f);
    }
}

// ---------------------------------------------------------------------------
extern "C" void kernel_launch(void* const* d_in, const int* in_sizes, int n_in,
                              void* d_out, int out_size, void* d_ws, size_t ws_size,
                              hipStream_t stream)
{
    const float* X    = (const float*)d_in[0];
    const float* alpha= (const float*)d_in[1];
    const float* w0a  = (const float*)d_in[2];
    const float* b0a  = (const float*)d_in[3];
    const float* w0b  = (const float*)d_in[4];
    const float* b0b  = (const float*)d_in[5];
    const float* W1a  = (const float*)d_in[6];
    const float* B1a  = (const float*)d_in[7];
    const float* W1b  = (const float*)d_in[8];
    const float* B1b  = (const float*)d_in[9];
    const int* esrc   = (const int*)d_in[10];
    const int* edst   = (const int*)d_in[11];
    float* y = (float*)d_out;

    // workspace layout (total ~58.4 MB)
    float* ego    = (float*)d_ws;
    float* outb   = ego  + (size_t)N_NODES * D_LAT;
    float* neig   = outb + (size_t)N_NODES * D_LAT;
    int*   off    = (int*)(neig + (size_t)N_NODES * D_LAT);  // N+1 (count->scan)
    int*   cursor = off + (N_NODES + 1);                      // N
    int*   part   = cursor + N_NODES;                         // 256
    int*   srcidx = part + 256;                               // E

    const int SCAN_BLOCKS = (N_NODES + 511) / 512;            // 250

    // CSR build (edges fixed -> amortized over 3 layers)
    hipMemsetAsync(off, 0, (N_NODES + 1) * sizeof(int), stream);
    k_hist<<<E_EDGES / 256, 256, 0, stream>>>(edst, off);
    k_scan1<<<SCAN_BLOCKS, 512, 0, stream>>>(off, part);
    k_scan2<<<1, 256, 0, stream>>>(part, SCAN_BLOCKS);
    k_scan3<<<SCAN_BLOCKS, 512, 0, stream>>>(off, part, cursor);
    k_fill<<<E_EDGES / 256, 256, 0, stream>>>(esrc, edst, cursor, srcidx);

    k_mlp0<<<N_NODES / 64, 256, 0, stream>>>(X, w0a, b0a, w0b, b0b, alpha, ego, outb);

    for (int l = 0; l < L_LAYERS; ++l) {
        k_gather<<<N_NODES / 32, 256, 0, stream>>>(ego, off, srcidx, neig);
        k_mlp1<<<N_NODES / 64, 256, 0, stream>>>(
            ego, neig, W1a + (size_t)l * 96 * 32, B1a + (size_t)l * 32,
            W1b + (size_t)l * 32 * 32, B1b + (size_t)l * 32, alpha, l, ego, outb);
    }

    k_topk<<<B_G, 256, 0, stream>>>(ego, outb, y);
}

// Round 4
// 594.198 us; speedup vs baseline: 17.9952x; 1.3149x over previous
//
#include <hip/hip_runtime.h>
#include <math.h>

#define N_NODES 128000
#define B_G 256
#define NPG 500
#define F_IN 128
#define D_LAT 32
#define K_TOP 30
#define L_LAYERS 3
#define E_EDGES 2048000

#define BSH 7                      // bucket = dst >> 7
#define NB (N_NODES >> BSH)        // 1000 buckets x 128 nodes
#define CHUNK 8192
#define CBLOCKS (E_EDGES / CHUNK)  // 250

// ---------------------------------------------------------------------------
// Kernel 1: ego = relu(X @ w0a + b0a) @ w0b + b0b ;  out = alpha[0] * ego
// ---------------------------------------------------------------------------
__global__ __launch_bounds__(256) void k_mlp0(
    const float* __restrict__ X, const float* __restrict__ w0a,
    const float* __restrict__ b0a, const float* __restrict__ w0b,
    const float* __restrict__ b0b, const float* __restrict__ alpha,
    float* __restrict__ ego, float* __restrict__ outb)
{
    __shared__ float sW0a[F_IN * D_LAT];
    __shared__ float sW0b[D_LAT * D_LAT];
    __shared__ float sB[2][D_LAT];
    __shared__ float sX[64 * F_IN];
    __shared__ float sH[64 * 33];

    const int t = threadIdx.x;
    const int blk = blockIdx.x;

    {
        const float4* s1 = (const float4*)w0a;  float4* d1 = (float4*)sW0a;
        for (int i = t; i < F_IN * D_LAT / 4; i += 256) d1[i] = s1[i];
        const float4* s2 = (const float4*)w0b;  float4* d2 = (float4*)sW0b;
        for (int i = t; i < D_LAT * D_LAT / 4; i += 256) d2[i] = s2[i];
        if (t < D_LAT) { sB[0][t] = b0a[t]; sB[1][t] = b0b[t]; }
    }
    {
        const float4* s = (const float4*)(X + (size_t)blk * 64 * F_IN);
        float4* d = (float4*)sX;
        for (int i = t; i < 64 * F_IN / 4; i += 256) d[i] = s[i];
    }
    __syncthreads();

    const int d = t & 31;
    const int rg = t >> 5;
    const float a0 = alpha[0];

    for (int rr = 0; rr < 8; ++rr) {
        const int r = rg * 8 + rr;
        float acc = sB[0][d];
        #pragma unroll 8
        for (int f = 0; f < F_IN; ++f)
            acc = fmaf(sX[r * F_IN + f], sW0a[f * D_LAT + d], acc);
        sH[r * 33 + d] = fmaxf(acc, 0.f);
    }
    __syncthreads();
    for (int rr = 0; rr < 8; ++rr) {
        const int r = rg * 8 + rr;
        float acc = sB[1][d];
        #pragma unroll
        for (int dd = 0; dd < D_LAT; ++dd)
            acc = fmaf(sH[r * 33 + dd], sW0b[dd * D_LAT + d], acc);
        const size_t gi = ((size_t)blk * 64 + r) * D_LAT + d;
        ego[gi] = acc;
        outb[gi] = a0 * acc;
    }
}

// ---------------------------------------------------------------------------
// Radix CSR build, step A: global bucket histogram via per-block LDS counts
// ---------------------------------------------------------------------------
__global__ __launch_bounds__(256) void k_bcount(
    const int* __restrict__ edst, int* __restrict__ ghist)
{
    __shared__ int cnt[NB];
    const int t = threadIdx.x;
    for (int i = t; i < NB; i += 256) cnt[i] = 0;
    __syncthreads();
    const int ebase = blockIdx.x * CHUNK;
    for (int i = 0; i < CHUNK / 256; ++i)
        atomicAdd(&cnt[edst[ebase + i * 256 + t] >> BSH], 1);
    __syncthreads();
    for (int i = t; i < NB; i += 256)
        if (cnt[i]) atomicAdd(&ghist[i], cnt[i]);
}

// Step B: exclusive scan of 1000 bucket counts; init cursors
__global__ __launch_bounds__(1024) void k_bscan(
    const int* __restrict__ ghist, int* __restrict__ gbase,
    int* __restrict__ gcursor)
{
    __shared__ int buf[2][1024];
    const int t = threadIdx.x;
    const int v = (t < NB) ? ghist[t] : 0;
    buf[0][t] = v;
    __syncthreads();
    int cur = 0;
    for (int o = 1; o < 1024; o <<= 1) {
        int x = buf[cur][t];
        if (t >= o) x += buf[cur][t - o];
        buf[cur ^ 1][t] = x;
        cur ^= 1;
        __syncthreads();
    }
    if (t < NB) { const int e = buf[cur][t] - v; gbase[t] = e; gcursor[t] = e; }
    if (t == 0) gbase[NB] = E_EDGES;
}

// Step C: scatter edges into bucket-contiguous packed runs.
// One atomic per (block,bucket); writes are ~8-int contiguous runs -> L2 merge.
__global__ __launch_bounds__(256) void k_bscatter(
    const int* __restrict__ esrc, const int* __restrict__ edst,
    int* __restrict__ gcursor, int* __restrict__ packed)
{
    __shared__ int cnt[NB];
    __shared__ int sbase[NB];
    const int t = threadIdx.x;
    for (int i = t; i < NB; i += 256) cnt[i] = 0;
    __syncthreads();
    const int ebase = blockIdx.x * CHUNK;
    for (int i = 0; i < CHUNK / 256; ++i)
        atomicAdd(&cnt[edst[ebase + i * 256 + t] >> BSH], 1);
    __syncthreads();
    for (int i = t; i < NB; i += 256) {
        const int c = cnt[i];
        sbase[i] = c ? atomicAdd(&gcursor[i], c) : 0;
        cnt[i] = 0;
    }
    __syncthreads();
    for (int i = 0; i < CHUNK / 256; ++i) {
        const int e = ebase + i * 256 + t;
        const int d = edst[e], s = esrc[e];
        const int b = d >> BSH;
        const int r = atomicAdd(&cnt[b], 1);
        packed[sbase[b] + r] = (s << BSH) | (d & ((1 << BSH) - 1));
    }
}

// Step D: per-bucket (128 nodes) CSR finalize fully in LDS; dense dumps.
__global__ __launch_bounds__(256) void k_bcsr(
    const int* __restrict__ gbase, const int* __restrict__ packed,
    int* __restrict__ off, int* __restrict__ srcidx)
{
    __shared__ int cnt[128];
    __shared__ int scn[128];
    __shared__ int sbuf[4096];     // max bucket load ~2300 << 4096
    const int b = blockIdx.x, t = threadIdx.x;
    const int s0 = gbase[b], s1 = gbase[b + 1], m = s1 - s0;

    if (t < 128) cnt[t] = 0;
    __syncthreads();
    for (int i = t; i < m; i += 256)
        atomicAdd(&cnt[packed[s0 + i] & 127], 1);
    __syncthreads();
    if (t == 0) {
        int a = 0;
        for (int k = 0; k < 128; ++k) { scn[k] = a; a += cnt[k]; }
    }
    __syncthreads();
    if (t < 128) { off[(b << BSH) + t] = s0 + scn[t]; cnt[t] = 0; }
    if (b == 0 && t == 0) off[N_NODES] = E_EDGES;
    __syncthreads();
    for (int i = t; i < m; i += 256) {
        const int p = packed[s0 + i];
        const int dl = p & 127;
        const int r = atomicAdd(&cnt[dl], 1);
        sbuf[scn[dl] + r] = p >> BSH;
    }
    __syncthreads();
    for (int i = t; i < m; i += 256) srcidx[s0 + i] = sbuf[i];
}

// ---------------------------------------------------------------------------
// Atomic-free SpMM gather: neig[n,:] = sum_{i in bucket(n)} ego[srcidx[i],:]
// ---------------------------------------------------------------------------
__global__ __launch_bounds__(256) void k_gather(
    const float* __restrict__ ego, const int* __restrict__ off,
    const int* __restrict__ srcidx, float* __restrict__ neig)
{
    const int t = threadIdx.x;
    const int node = blockIdx.x * 32 + (t >> 3);
    const int c = (t & 7) * 4;
    const int s0 = off[node], s1 = off[node + 1];
    float4 acc = {0.f, 0.f, 0.f, 0.f};
    for (int i = s0; i < s1; ++i) {
        const int s = srcidx[i];
        const float4 v = *(const float4*)(ego + (size_t)s * D_LAT + c);
        acc.x += v.x; acc.y += v.y; acc.z += v.z; acc.w += v.w;
    }
    *(float4*)(neig + (size_t)node * D_LAT + c) = acc;
}

// ---------------------------------------------------------------------------
// Per-layer combine (concat folded algebraically)
// ---------------------------------------------------------------------------
__global__ __launch_bounds__(256) void k_mlp1(
    const float* __restrict__ ego_in, const float* __restrict__ neig,
    const float* __restrict__ W1a_l, const float* __restrict__ B1a_l,
    const float* __restrict__ W1b_l, const float* __restrict__ B1b_l,
    const float* __restrict__ alpha, const int l,
    float* __restrict__ ego_out, float* __restrict__ outb)
{
    __shared__ float sWe[32 * 32], sWn[32 * 32], sWb[32 * 32];
    __shared__ float sB[2][32];
    __shared__ float sE[64 * 32], sNg[64 * 32];
    __shared__ float sH[64 * 33];

    const int t = threadIdx.x;
    const int blk = blockIdx.x;

    for (int i = t; i < 1024; i += 256) {
        const float wc = W1a_l[2048 + i];
        sWe[i] = W1a_l[i] + wc;
        sWn[i] = W1a_l[1024 + i] + wc;
        sWb[i] = W1b_l[i];
    }
    if (t < 32) { sB[0][t] = B1a_l[t]; sB[1][t] = B1b_l[t]; }
    {
        const float4* se = (const float4*)(ego_in + (size_t)blk * 64 * 32);
        const float4* sn = (const float4*)(neig  + (size_t)blk * 64 * 32);
        float4* de = (float4*)sE; float4* dn4 = (float4*)sNg;
        for (int i = t; i < 512; i += 256) { de[i] = se[i]; dn4[i] = sn[i]; }
    }
    __syncthreads();

    const int d = t & 31;
    const int rg = t >> 5;
    const float al = alpha[l + 1];

    for (int rr = 0; rr < 8; ++rr) {
        const int r = rg * 8 + rr;
        float acc = sB[0][d];
        #pragma unroll
        for (int dd = 0; dd < 32; ++dd)
            acc = fmaf(sE[r * 32 + dd], sWe[dd * 32 + d],
                       fmaf(sNg[r * 32 + dd], sWn[dd * 32 + d], acc));
        sH[r * 33 + d] = fmaxf(acc, 0.f);
    }
    __syncthreads();
    for (int rr = 0; rr < 8; ++rr) {
        const int r = rg * 8 + rr;
        float acc = sB[1][d];
        #pragma unroll
        for (int dd = 0; dd < 32; ++dd)
            acc = fmaf(sH[r * 33 + dd], sWb[dd * 32 + d], acc);
        const size_t gi = ((size_t)blk * 64 + r) * 32 + d;
        ego_out[gi] = acc;
        outb[gi] += al * acc;
    }
}

// ---------------------------------------------------------------------------
// Per-graph top-30 on ego[:,31] (stable ties -> smaller index) + gather + relu
// ---------------------------------------------------------------------------
__global__ __launch_bounds__(256) void k_topk(
    const float* __restrict__ ego, const float* __restrict__ outb,
    float* __restrict__ y)
{
    __shared__ float vals[512];
    __shared__ int topidx[K_TOP];
    __shared__ float wv[4];
    __shared__ int wi[4];

    const int g = blockIdx.x, t = threadIdx.x;
    for (int i = t; i < 512; i += 256)
        vals[i] = (i < NPG) ? ego[((size_t)g * NPG + i) * D_LAT + (D_LAT - 1)]
                            : -INFINITY;
    __syncthreads();

    for (int k = 0; k < K_TOP; ++k) {
        float v = -INFINITY; int bi = 0x7fffffff;
        for (int i = t; i < NPG; i += 256) {
            const float x = vals[i];
            if (x > v || (x == v && i < bi)) { v = x; bi = i; }
        }
        for (int off = 32; off > 0; off >>= 1) {
            const float ov = __shfl_down(v, off);
            const int   oi = __shfl_down(bi, off);
            if (ov > v || (ov == v && oi < bi)) { v = ov; bi = oi; }
        }
        if ((t & 63) == 0) { wv[t >> 6] = v; wi[t >> 6] = bi; }
        __syncthreads();
        if (t == 0) {
            for (int w = 1; w < 4; ++w)
                if (wv[w] > v || (wv[w] == v && wi[w] < bi)) { v = wv[w]; bi = wi[w]; }
            topidx[k] = bi;
            vals[bi] = -INFINITY;
        }
        __syncthreads();
    }

    for (int j = t; j < K_TOP * D_LAT; j += 256) {
        const int kk = j >> 5, d = j & 31;
        const size_t node = (size_t)g * NPG + topidx[kk];
        y[(size_t)g * (K_TOP * D_LAT) + j] = fmaxf(outb[node * D_LAT + d], 0.f);
    }
}

// ---------------------------------------------------------------------------
extern "C" void kernel_launch(void* const* d_in, const int* in_sizes, int n_in,
                              void* d_out, int out_size, void* d_ws, size_t ws_size,
                              hipStream_t stream)
{
    const float* X    = (const float*)d_in[0];
    const float* alpha= (const float*)d_in[1];
    const float* w0a  = (const float*)d_in[2];
    const float* b0a  = (const float*)d_in[3];
    const float* w0b  = (const float*)d_in[4];
    const float* b0b  = (const float*)d_in[5];
    const float* W1a  = (const float*)d_in[6];
    const float* B1a  = (const float*)d_in[7];
    const float* W1b  = (const float*)d_in[8];
    const float* B1b  = (const float*)d_in[9];
    const int* esrc   = (const int*)d_in[10];
    const int* edst   = (const int*)d_in[11];
    float* y = (float*)d_out;

    // workspace layout (~57.9 MB)
    float* ego    = (float*)d_ws;
    float* outb   = ego  + (size_t)N_NODES * D_LAT;
    float* neig   = outb + (size_t)N_NODES * D_LAT;
    int*   packed = (int*)neig;                              // alias: dead before 1st gather
    int*   off    = (int*)(neig + (size_t)N_NODES * D_LAT);  // N+1
    int*   srcidx = off + (N_NODES + 1);                     // E
    int*   ghist  = srcidx + E_EDGES;                        // NB
    int*   gbase  = ghist + NB;                              // NB+1
    int*   gcursor= gbase + (NB + 1);                        // NB

    // CSR build (radix by dst>>7, dense writes)
    hipMemsetAsync(ghist, 0, NB * sizeof(int), stream);
    k_bcount  <<<CBLOCKS, 256, 0, stream>>>(edst, ghist);
    k_bscan   <<<1, 1024, 0, stream>>>(ghist, gbase, gcursor);
    k_bscatter<<<CBLOCKS, 256, 0, stream>>>(esrc, edst, gcursor, packed);
    k_bcsr    <<<NB, 256, 0, stream>>>(gbase, packed, off, srcidx);

    k_mlp0<<<N_NODES / 64, 256, 0, stream>>>(X, w0a, b0a, w0b, b0b, alpha, ego, outb);

    for (int l = 0; l < L_LAYERS; ++l) {
        k_gather<<<N_NODES / 32, 256, 0, stream>>>(ego, off, srcidx, neig);
        k_mlp1<<<N_NODES / 64, 256, 0, stream>>>(
            ego, neig, W1a + (size_t)l * 96 * 32, B1a + (size_t)l * 32,
            W1b + (size_t)l * 32 * 32, B1b + (size_t)l * 32, alpha, l, ego, outb);
    }

    k_topk<<<B_G, 256, 0, stream>>>(ego, outb, y);
}

// Round 5
// 509.807 us; speedup vs baseline: 20.9740x; 1.1655x over previous
//
#include <hip/hip_runtime.h>
#include <math.h>

#define N_NODES 128000
#define B_G 256
#define NPG 500
#define F_IN 128
#define D_LAT 32
#define K_TOP 30
#define L_LAYERS 3
#define E_EDGES 2048000

#define BSH 7                      // bucket = dst >> 7
#define NB (N_NODES >> BSH)        // 1000 buckets x 128 nodes
#define CHUNK 8192
#define CBLOCKS (E_EDGES / CHUNK)  // 250

// ---------------------------------------------------------------------------
// Kernel 1: ego = relu(X @ w0a + b0a) @ w0b + b0b ;  out = alpha[0] * ego
// Register-GEMM: thread = row. X row streamed to VGPRs (full 128B lines),
// acc[32] in VGPRs, weights read as wave-uniform ds_read_b128 broadcasts.
// ---------------------------------------------------------------------------
__global__ __launch_bounds__(256) void k_mlp0(
    const float* __restrict__ X, const float* __restrict__ w0a,
    const float* __restrict__ b0a, const float* __restrict__ w0b,
    const float* __restrict__ b0b, const float* __restrict__ alpha,
    float* __restrict__ ego, float* __restrict__ outb)
{
    __shared__ float sWa[F_IN * D_LAT];   // 16 KB [f][d]
    __shared__ float sWb[D_LAT * D_LAT];  // 4 KB  [dd][d]
    __shared__ float sBa[D_LAT], sBb[D_LAT];

    const int t = threadIdx.x;
    for (int i = t; i < F_IN * D_LAT / 4; i += 256)
        ((float4*)sWa)[i] = ((const float4*)w0a)[i];
    for (int i = t; i < D_LAT * D_LAT / 4; i += 256)
        ((float4*)sWb)[i] = ((const float4*)w0b)[i];
    if (t < D_LAT) { sBa[t] = b0a[t]; sBb[t] = b0b[t]; }

    const size_t row = (size_t)blockIdx.x * 256 + t;
    const float4* xp = (const float4*)(X + row * F_IN);
    const float a0 = alpha[0];
    __syncthreads();

    float acc[D_LAT];
    #pragma unroll
    for (int d = 0; d < D_LAT; ++d) acc[d] = sBa[d];

    // stage 1: 128 -> 32, 16 f's per chunk (4 float4 row regs live)
    #pragma unroll
    for (int c = 0; c < F_IN / 16; ++c) {
        float4 x4[4];
        #pragma unroll
        for (int q = 0; q < 4; ++q) x4[q] = xp[c * 4 + q];
        #pragma unroll
        for (int q = 0; q < 4; ++q) {
            const float xs[4] = {x4[q].x, x4[q].y, x4[q].z, x4[q].w};
            #pragma unroll
            for (int ff = 0; ff < 4; ++ff) {
                const float xf = xs[ff];
                const float4* wr = (const float4*)(sWa + (c * 16 + q * 4 + ff) * D_LAT);
                #pragma unroll
                for (int dq = 0; dq < D_LAT / 4; ++dq) {
                    const float4 w = wr[dq];
                    acc[dq * 4 + 0] = fmaf(xf, w.x, acc[dq * 4 + 0]);
                    acc[dq * 4 + 1] = fmaf(xf, w.y, acc[dq * 4 + 1]);
                    acc[dq * 4 + 2] = fmaf(xf, w.z, acc[dq * 4 + 2]);
                    acc[dq * 4 + 3] = fmaf(xf, w.w, acc[dq * 4 + 3]);
                }
            }
        }
    }

    // stage 2: relu -> 32x32, all in registers
    float acc2[D_LAT];
    #pragma unroll
    for (int d = 0; d < D_LAT; ++d) acc2[d] = sBb[d];
    #pragma unroll
    for (int dd = 0; dd < D_LAT; ++dd) {
        const float h = fmaxf(acc[dd], 0.f);
        const float4* wr = (const float4*)(sWb + dd * D_LAT);
        #pragma unroll
        for (int dq = 0; dq < D_LAT / 4; ++dq) {
            const float4 w = wr[dq];
            acc2[dq * 4 + 0] = fmaf(h, w.x, acc2[dq * 4 + 0]);
            acc2[dq * 4 + 1] = fmaf(h, w.y, acc2[dq * 4 + 1]);
            acc2[dq * 4 + 2] = fmaf(h, w.z, acc2[dq * 4 + 2]);
            acc2[dq * 4 + 3] = fmaf(h, w.w, acc2[dq * 4 + 3]);
        }
    }

    float4* eo = (float4*)(ego + row * D_LAT);
    float4* oo = (float4*)(outb + row * D_LAT);
    #pragma unroll
    for (int dq = 0; dq < D_LAT / 4; ++dq) {
        eo[dq] = make_float4(acc2[dq*4], acc2[dq*4+1], acc2[dq*4+2], acc2[dq*4+3]);
        oo[dq] = make_float4(a0*acc2[dq*4], a0*acc2[dq*4+1], a0*acc2[dq*4+2], a0*acc2[dq*4+3]);
    }
}

// ---------------------------------------------------------------------------
// Radix CSR build (unchanged from round 4)
// ---------------------------------------------------------------------------
__global__ __launch_bounds__(256) void k_bcount(
    const int* __restrict__ edst, int* __restrict__ ghist)
{
    __shared__ int cnt[NB];
    const int t = threadIdx.x;
    for (int i = t; i < NB; i += 256) cnt[i] = 0;
    __syncthreads();
    const int ebase = blockIdx.x * CHUNK;
    for (int i = 0; i < CHUNK / 256; ++i)
        atomicAdd(&cnt[edst[ebase + i * 256 + t] >> BSH], 1);
    __syncthreads();
    for (int i = t; i < NB; i += 256)
        if (cnt[i]) atomicAdd(&ghist[i], cnt[i]);
}

__global__ __launch_bounds__(1024) void k_bscan(
    const int* __restrict__ ghist, int* __restrict__ gbase,
    int* __restrict__ gcursor)
{
    __shared__ int buf[2][1024];
    const int t = threadIdx.x;
    const int v = (t < NB) ? ghist[t] : 0;
    buf[0][t] = v;
    __syncthreads();
    int cur = 0;
    for (int o = 1; o < 1024; o <<= 1) {
        int x = buf[cur][t];
        if (t >= o) x += buf[cur][t - o];
        buf[cur ^ 1][t] = x;
        cur ^= 1;
        __syncthreads();
    }
    if (t < NB) { const int e = buf[cur][t] - v; gbase[t] = e; gcursor[t] = e; }
    if (t == 0) gbase[NB] = E_EDGES;
}

__global__ __launch_bounds__(256) void k_bscatter(
    const int* __restrict__ esrc, const int* __restrict__ edst,
    int* __restrict__ gcursor, int* __restrict__ packed)
{
    __shared__ int cnt[NB];
    __shared__ int sbase[NB];
    const int t = threadIdx.x;
    for (int i = t; i < NB; i += 256) cnt[i] = 0;
    __syncthreads();
    const int ebase = blockIdx.x * CHUNK;
    for (int i = 0; i < CHUNK / 256; ++i)
        atomicAdd(&cnt[edst[ebase + i * 256 + t] >> BSH], 1);
    __syncthreads();
    for (int i = t; i < NB; i += 256) {
        const int c = cnt[i];
        sbase[i] = c ? atomicAdd(&gcursor[i], c) : 0;
        cnt[i] = 0;
    }
    __syncthreads();
    for (int i = 0; i < CHUNK / 256; ++i) {
        const int e = ebase + i * 256 + t;
        const int d = edst[e], s = esrc[e];
        const int b = d >> BSH;
        const int r = atomicAdd(&cnt[b], 1);
        packed[sbase[b] + r] = (s << BSH) | (d & ((1 << BSH) - 1));
    }
}

__global__ __launch_bounds__(256) void k_bcsr(
    const int* __restrict__ gbase, const int* __restrict__ packed,
    int* __restrict__ off, int* __restrict__ srcidx)
{
    __shared__ int cnt[128];
    __shared__ int scn[128];
    __shared__ int sbuf[4096];
    const int b = blockIdx.x, t = threadIdx.x;
    const int s0 = gbase[b], s1 = gbase[b + 1], m = s1 - s0;

    if (t < 128) cnt[t] = 0;
    __syncthreads();
    for (int i = t; i < m; i += 256)
        atomicAdd(&cnt[packed[s0 + i] & 127], 1);
    __syncthreads();
    if (t == 0) {
        int a = 0;
        for (int k = 0; k < 128; ++k) { scn[k] = a; a += cnt[k]; }
    }
    __syncthreads();
    if (t < 128) { off[(b << BSH) + t] = s0 + scn[t]; cnt[t] = 0; }
    if (b == 0 && t == 0) off[N_NODES] = E_EDGES;
    __syncthreads();
    for (int i = t; i < m; i += 256) {
        const int p = packed[s0 + i];
        const int dl = p & 127;
        const int r = atomicAdd(&cnt[dl], 1);
        sbuf[scn[dl] + r] = p >> BSH;
    }
    __syncthreads();
    for (int i = t; i < m; i += 256) srcidx[s0 + i] = sbuf[i];
}

// ---------------------------------------------------------------------------
// Atomic-free SpMM gather (unchanged)
// ---------------------------------------------------------------------------
__global__ __launch_bounds__(256) void k_gather(
    const float* __restrict__ ego, const int* __restrict__ off,
    const int* __restrict__ srcidx, float* __restrict__ neig)
{
    const int t = threadIdx.x;
    const int node = blockIdx.x * 32 + (t >> 3);
    const int c = (t & 7) * 4;
    const int s0 = off[node], s1 = off[node + 1];
    float4 acc = {0.f, 0.f, 0.f, 0.f};
    for (int i = s0; i < s1; ++i) {
        const int s = srcidx[i];
        const float4 v = *(const float4*)(ego + (size_t)s * D_LAT + c);
        acc.x += v.x; acc.y += v.y; acc.z += v.z; acc.w += v.w;
    }
    *(float4*)(neig + (size_t)node * D_LAT + c) = acc;
}

// ---------------------------------------------------------------------------
// Kernel 3: per-layer combine, register-GEMM (concat folded algebraically)
// thread = row; ego/neig rows streamed to VGPRs; weights broadcast from LDS.
// ---------------------------------------------------------------------------
__global__ __launch_bounds__(256) void k_mlp1(
    const float* __restrict__ ego_in, const float* __restrict__ neig,
    const float* __restrict__ W1a_l, const float* __restrict__ B1a_l,
    const float* __restrict__ W1b_l, const float* __restrict__ B1b_l,
    const float* __restrict__ alpha, const int l,
    float* __restrict__ ego_out, float* __restrict__ outb)
{
    __shared__ float sWe[D_LAT * D_LAT], sWn[D_LAT * D_LAT], sWb[D_LAT * D_LAT];
    __shared__ float sBa[D_LAT], sBb[D_LAT];

    const int t = threadIdx.x;
    for (int i = t; i < D_LAT * D_LAT; i += 256) {
        const float wc = W1a_l[2 * D_LAT * D_LAT + i];   // rows 64..95 (n+e part)
        sWe[i] = W1a_l[i] + wc;
        sWn[i] = W1a_l[D_LAT * D_LAT + i] + wc;
        sWb[i] = W1b_l[i];
    }
    if (t < D_LAT) { sBa[t] = B1a_l[t]; sBb[t] = B1b_l[t]; }

    const size_t row = (size_t)blockIdx.x * 256 + t;
    const float4* ep = (const float4*)(ego_in + row * D_LAT);
    const float4* np_ = (const float4*)(neig + row * D_LAT);
    const float al = alpha[l + 1];
    __syncthreads();

    float acc[D_LAT];
    #pragma unroll
    for (int d = 0; d < D_LAT; ++d) acc[d] = sBa[d];

    #pragma unroll
    for (int c = 0; c < D_LAT / 4; ++c) {
        const float4 e4 = ep[c];
        const float4 n4 = np_[c];
        const float es[4] = {e4.x, e4.y, e4.z, e4.w};
        const float ns[4] = {n4.x, n4.y, n4.z, n4.w};
        #pragma unroll
        for (int ff = 0; ff < 4; ++ff) {
            const float fe = es[ff], fn = ns[ff];
            const float4* we = (const float4*)(sWe + (c * 4 + ff) * D_LAT);
            const float4* wn = (const float4*)(sWn + (c * 4 + ff) * D_LAT);
            #pragma unroll
            for (int dq = 0; dq < D_LAT / 4; ++dq) {
                const float4 a = we[dq], b = wn[dq];
                acc[dq * 4 + 0] = fmaf(fe, a.x, fmaf(fn, b.x, acc[dq * 4 + 0]));
                acc[dq * 4 + 1] = fmaf(fe, a.y, fmaf(fn, b.y, acc[dq * 4 + 1]));
                acc[dq * 4 + 2] = fmaf(fe, a.z, fmaf(fn, b.z, acc[dq * 4 + 2]));
                acc[dq * 4 + 3] = fmaf(fe, a.w, fmaf(fn, b.w, acc[dq * 4 + 3]));
            }
        }
    }

    float acc2[D_LAT];
    #pragma unroll
    for (int d = 0; d < D_LAT; ++d) acc2[d] = sBb[d];
    #pragma unroll
    for (int dd = 0; dd < D_LAT; ++dd) {
        const float h = fmaxf(acc[dd], 0.f);
        const float4* wr = (const float4*)(sWb + dd * D_LAT);
        #pragma unroll
        for (int dq = 0; dq < D_LAT / 4; ++dq) {
            const float4 w = wr[dq];
            acc2[dq * 4 + 0] = fmaf(h, w.x, acc2[dq * 4 + 0]);
            acc2[dq * 4 + 1] = fmaf(h, w.y, acc2[dq * 4 + 1]);
            acc2[dq * 4 + 2] = fmaf(h, w.z, acc2[dq * 4 + 2]);
            acc2[dq * 4 + 3] = fmaf(h, w.w, acc2[dq * 4 + 3]);
        }
    }

    float4* eo = (float4*)(ego_out + row * D_LAT);
    float4* oo = (float4*)(outb + row * D_LAT);
    #pragma unroll
    for (int dq = 0; dq < D_LAT / 4; ++dq) {
        const float4 prev = oo[dq];
        eo[dq] = make_float4(acc2[dq*4], acc2[dq*4+1], acc2[dq*4+2], acc2[dq*4+3]);
        oo[dq] = make_float4(fmaf(al, acc2[dq*4], prev.x),
                             fmaf(al, acc2[dq*4+1], prev.y),
                             fmaf(al, acc2[dq*4+2], prev.z),
                             fmaf(al, acc2[dq*4+3], prev.w));
    }
}

// ---------------------------------------------------------------------------
// Per-graph top-30 (stable ties -> smaller index) + gather + relu (unchanged)
// ---------------------------------------------------------------------------
__global__ __launch_bounds__(256) void k_topk(
    const float* __restrict__ ego, const float* __restrict__ outb,
    float* __restrict__ y)
{
    __shared__ float vals[512];
    __shared__ int topidx[K_TOP];
    __shared__ float wv[4];
    __shared__ int wi[4];

    const int g = blockIdx.x, t = threadIdx.x;
    for (int i = t; i < 512; i += 256)
        vals[i] = (i < NPG) ? ego[((size_t)g * NPG + i) * D_LAT + (D_LAT - 1)]
                            : -INFINITY;
    __syncthreads();

    for (int k = 0; k < K_TOP; ++k) {
        float v = -INFINITY; int bi = 0x7fffffff;
        for (int i = t; i < NPG; i += 256) {
            const float x = vals[i];
            if (x > v || (x == v && i < bi)) { v = x; bi = i; }
        }
        for (int off = 32; off > 0; off >>= 1) {
            const float ov = __shfl_down(v, off);
            const int   oi = __shfl_down(bi, off);
            if (ov > v || (ov == v && oi < bi)) { v = ov; bi = oi; }
        }
        if ((t & 63) == 0) { wv[t >> 6] = v; wi[t >> 6] = bi; }
        __syncthreads();
        if (t == 0) {
            for (int w = 1; w < 4; ++w)
                if (wv[w] > v || (wv[w] == v && wi[w] < bi)) { v = wv[w]; bi = wi[w]; }
            topidx[k] = bi;
            vals[bi] = -INFINITY;
        }
        __syncthreads();
    }

    for (int j = t; j < K_TOP * D_LAT; j += 256) {
        const int kk = j >> 5, d = j & 31;
        const size_t node = (size_t)g * NPG + topidx[kk];
        y[(size_t)g * (K_TOP * D_LAT) + j] = fmaxf(outb[node * D_LAT + d], 0.f);
    }
}

// ---------------------------------------------------------------------------
extern "C" void kernel_launch(void* const* d_in, const int* in_sizes, int n_in,
                              void* d_out, int out_size, void* d_ws, size_t ws_size,
                              hipStream_t stream)
{
    const float* X    = (const float*)d_in[0];
    const float* alpha= (const float*)d_in[1];
    const float* w0a  = (const float*)d_in[2];
    const float* b0a  = (const float*)d_in[3];
    const float* w0b  = (const float*)d_in[4];
    const float* b0b  = (const float*)d_in[5];
    const float* W1a  = (const float*)d_in[6];
    const float* B1a  = (const float*)d_in[7];
    const float* W1b  = (const float*)d_in[8];
    const float* B1b  = (const float*)d_in[9];
    const int* esrc   = (const int*)d_in[10];
    const int* edst   = (const int*)d_in[11];
    float* y = (float*)d_out;

    float* ego    = (float*)d_ws;
    float* outb   = ego  + (size_t)N_NODES * D_LAT;
    float* neig   = outb + (size_t)N_NODES * D_LAT;
    int*   packed = (int*)neig;                              // alias: dead before 1st gather
    int*   off    = (int*)(neig + (size_t)N_NODES * D_LAT);  // N+1
    int*   srcidx = off + (N_NODES + 1);                     // E
    int*   ghist  = srcidx + E_EDGES;                        // NB
    int*   gbase  = ghist + NB;                              // NB+1
    int*   gcursor= gbase + (NB + 1);                        // NB

    hipMemsetAsync(ghist, 0, NB * sizeof(int), stream);
    k_bcount  <<<CBLOCKS, 256, 0, stream>>>(edst, ghist);
    k_bscan   <<<1, 1024, 0, stream>>>(ghist, gbase, gcursor);
    k_bscatter<<<CBLOCKS, 256, 0, stream>>>(esrc, edst, gcursor, packed);
    k_bcsr    <<<NB, 256, 0, stream>>>(gbase, packed, off, srcidx);

    k_mlp0<<<N_NODES / 256, 256, 0, stream>>>(X, w0a, b0a, w0b, b0b, alpha, ego, outb);

    for (int l = 0; l < L_LAYERS; ++l) {
        k_gather<<<N_NODES / 32, 256, 0, stream>>>(ego, off, srcidx, neig);
        k_mlp1<<<N_NODES / 256, 256, 0, stream>>>(
            ego, neig, W1a + (size_t)l * 96 * 32, B1a + (size_t)l * 32,
            W1b + (size_t)l * 32 * 32, B1b + (size_t)l * 32, alpha, l, ego, outb);
    }

    k_topk<<<B_G, 256, 0, stream>>>(ego, outb, y);
}

// Round 6
// 469.262 us; speedup vs baseline: 22.7862x; 1.0864x over previous
//
#include <hip/hip_runtime.h>
#include <math.h>

#define N_NODES 128000
#define B_G 256
#define NPG 500
#define F_IN 128
#define D_LAT 32
#define K_TOP 30
#define L_LAYERS 3
#define E_EDGES 2048000

#define BSH 7                      // bucket = dst >> 7
#define NB (N_NODES >> BSH)        // 1000 buckets x 128 nodes
#define CHUNK 8192
#define CBLOCKS (E_EDGES / CHUNK)  // 250

// ---------------------------------------------------------------------------
// Kernel 1: ego = relu(X @ w0a + b0a) @ w0b + b0b ;  out = alpha[0] * ego
// Split-K register-GEMM: 2 threads per row (even lane: f 0..63, odd: 64..127).
// #pragma unroll 1 on the chunk loop pins acc[32] in VGPRs (prevents the
// loop-distribution that produced VGPR=40 + X re-reads in round 5).
// ---------------------------------------------------------------------------
__global__ __launch_bounds__(256) void k_mlp0(
    const float* __restrict__ X, const float* __restrict__ w0a,
    const float* __restrict__ b0a, const float* __restrict__ w0b,
    const float* __restrict__ b0b, const float* __restrict__ alpha,
    float* __restrict__ ego, float* __restrict__ outb)
{
    __shared__ float sWa[F_IN * D_LAT];   // 16 KB [f][d]
    __shared__ float sWb[D_LAT * D_LAT];  // 4 KB  [dd][d]
    __shared__ float sBa[D_LAT], sBb[D_LAT];

    const int t = threadIdx.x;
    for (int i = t; i < F_IN * D_LAT / 4; i += 256)
        ((float4*)sWa)[i] = ((const float4*)w0a)[i];
    for (int i = t; i < D_LAT * D_LAT / 4; i += 256)
        ((float4*)sWb)[i] = ((const float4*)w0b)[i];
    if (t < D_LAT) { sBa[t] = b0a[t]; sBb[t] = b0b[t]; }

    const int gtid = blockIdx.x * 256 + t;
    const size_t row = (size_t)(gtid >> 1);
    const int half = gtid & 1;
    const float4* xp = (const float4*)(X + row * F_IN + half * 64);
    const float* wbase = sWa + half * 64 * D_LAT;
    const float a0 = alpha[0];
    __syncthreads();

    float acc[D_LAT];
    #pragma unroll
    for (int d = 0; d < D_LAT; ++d) acc[d] = 0.f;

    // stage 1 partial: 64 features, chunks of 8 (outer loop NOT unrolled)
    #pragma unroll 1
    for (int c = 0; c < 8; ++c) {
        const float4 xa = xp[c * 2], xb = xp[c * 2 + 1];
        const float xs[8] = {xa.x, xa.y, xa.z, xa.w, xb.x, xb.y, xb.z, xb.w};
        #pragma unroll
        for (int ff = 0; ff < 8; ++ff) {
            const float xf = xs[ff];
            const float4* wr = (const float4*)(wbase + (c * 8 + ff) * D_LAT);
            #pragma unroll
            for (int dq = 0; dq < D_LAT / 4; ++dq) {
                const float4 w = wr[dq];
                acc[dq * 4 + 0] = fmaf(xf, w.x, acc[dq * 4 + 0]);
                acc[dq * 4 + 1] = fmaf(xf, w.y, acc[dq * 4 + 1]);
                acc[dq * 4 + 2] = fmaf(xf, w.z, acc[dq * 4 + 2]);
                acc[dq * 4 + 3] = fmaf(xf, w.w, acc[dq * 4 + 3]);
            }
        }
    }

    // combine K-halves (lane pairs), bias, relu
    float h[D_LAT];
    #pragma unroll
    for (int d = 0; d < D_LAT; ++d) {
        const float s = acc[d] + __shfl_xor(acc[d], 1);
        h[d] = fmaxf(s + sBa[d], 0.f);
    }

    // stage 2: this lane computes 16 output cols [half*16 .. half*16+15]
    float acc2[16];
    #pragma unroll
    for (int j = 0; j < 16; ++j) acc2[j] = sBb[half * 16 + j];
    #pragma unroll
    for (int dd = 0; dd < D_LAT; ++dd) {
        const float hd = h[dd];
        const float4* wr = (const float4*)(sWb + dd * D_LAT + half * 16);
        #pragma unroll
        for (int q = 0; q < 4; ++q) {
            const float4 w = wr[q];
            acc2[q * 4 + 0] = fmaf(hd, w.x, acc2[q * 4 + 0]);
            acc2[q * 4 + 1] = fmaf(hd, w.y, acc2[q * 4 + 1]);
            acc2[q * 4 + 2] = fmaf(hd, w.z, acc2[q * 4 + 2]);
            acc2[q * 4 + 3] = fmaf(hd, w.w, acc2[q * 4 + 3]);
        }
    }

    float4* eo = (float4*)(ego + row * D_LAT + half * 16);
    float4* oo = (float4*)(outb + row * D_LAT + half * 16);
    #pragma unroll
    for (int q = 0; q < 4; ++q) {
        eo[q] = make_float4(acc2[q*4], acc2[q*4+1], acc2[q*4+2], acc2[q*4+3]);
        oo[q] = make_float4(a0*acc2[q*4], a0*acc2[q*4+1], a0*acc2[q*4+2], a0*acc2[q*4+3]);
    }
}

// ---------------------------------------------------------------------------
// Radix CSR build (unchanged)
// ---------------------------------------------------------------------------
__global__ __launch_bounds__(256) void k_bcount(
    const int* __restrict__ edst, int* __restrict__ ghist)
{
    __shared__ int cnt[NB];
    const int t = threadIdx.x;
    for (int i = t; i < NB; i += 256) cnt[i] = 0;
    __syncthreads();
    const int ebase = blockIdx.x * CHUNK;
    for (int i = 0; i < CHUNK / 256; ++i)
        atomicAdd(&cnt[edst[ebase + i * 256 + t] >> BSH], 1);
    __syncthreads();
    for (int i = t; i < NB; i += 256)
        if (cnt[i]) atomicAdd(&ghist[i], cnt[i]);
}

__global__ __launch_bounds__(1024) void k_bscan(
    const int* __restrict__ ghist, int* __restrict__ gbase,
    int* __restrict__ gcursor)
{
    __shared__ int buf[2][1024];
    const int t = threadIdx.x;
    const int v = (t < NB) ? ghist[t] : 0;
    buf[0][t] = v;
    __syncthreads();
    int cur = 0;
    for (int o = 1; o < 1024; o <<= 1) {
        int x = buf[cur][t];
        if (t >= o) x += buf[cur][t - o];
        buf[cur ^ 1][t] = x;
        cur ^= 1;
        __syncthreads();
    }
    if (t < NB) { const int e = buf[cur][t] - v; gbase[t] = e; gcursor[t] = e; }
    if (t == 0) gbase[NB] = E_EDGES;
}

__global__ __launch_bounds__(256) void k_bscatter(
    const int* __restrict__ esrc, const int* __restrict__ edst,
    int* __restrict__ gcursor, int* __restrict__ packed)
{
    __shared__ int cnt[NB];
    __shared__ int sbase[NB];
    const int t = threadIdx.x;
    for (int i = t; i < NB; i += 256) cnt[i] = 0;
    __syncthreads();
    const int ebase = blockIdx.x * CHUNK;
    for (int i = 0; i < CHUNK / 256; ++i)
        atomicAdd(&cnt[edst[ebase + i * 256 + t] >> BSH], 1);
    __syncthreads();
    for (int i = t; i < NB; i += 256) {
        const int c = cnt[i];
        sbase[i] = c ? atomicAdd(&gcursor[i], c) : 0;
        cnt[i] = 0;
    }
    __syncthreads();
    for (int i = 0; i < CHUNK / 256; ++i) {
        const int e = ebase + i * 256 + t;
        const int d = edst[e], s = esrc[e];
        const int b = d >> BSH;
        const int r = atomicAdd(&cnt[b], 1);
        packed[sbase[b] + r] = (s << BSH) | (d & ((1 << BSH) - 1));
    }
}

__global__ __launch_bounds__(256) void k_bcsr(
    const int* __restrict__ gbase, const int* __restrict__ packed,
    int* __restrict__ off, int* __restrict__ srcidx)
{
    __shared__ int cnt[128];
    __shared__ int scn[128];
    __shared__ int sbuf[4096];
    const int b = blockIdx.x, t = threadIdx.x;
    const int s0 = gbase[b], s1 = gbase[b + 1], m = s1 - s0;

    if (t < 128) cnt[t] = 0;
    __syncthreads();
    for (int i = t; i < m; i += 256)
        atomicAdd(&cnt[packed[s0 + i] & 127], 1);
    __syncthreads();
    if (t == 0) {
        int a = 0;
        for (int k = 0; k < 128; ++k) { scn[k] = a; a += cnt[k]; }
    }
    __syncthreads();
    if (t < 128) { off[(b << BSH) + t] = s0 + scn[t]; cnt[t] = 0; }
    if (b == 0 && t == 0) off[N_NODES] = E_EDGES;
    __syncthreads();
    for (int i = t; i < m; i += 256) {
        const int p = packed[s0 + i];
        const int dl = p & 127;
        const int r = atomicAdd(&cnt[dl], 1);
        sbuf[scn[dl] + r] = p >> BSH;
    }
    __syncthreads();
    for (int i = t; i < m; i += 256) srcidx[s0 + i] = sbuf[i];
}

// ---------------------------------------------------------------------------
// Atomic-free SpMM gather (unchanged)
// ---------------------------------------------------------------------------
__global__ __launch_bounds__(256) void k_gather(
    const float* __restrict__ ego, const int* __restrict__ off,
    const int* __restrict__ srcidx, float* __restrict__ neig)
{
    const int t = threadIdx.x;
    const int node = blockIdx.x * 32 + (t >> 3);
    const int c = (t & 7) * 4;
    const int s0 = off[node], s1 = off[node + 1];
    float4 acc = {0.f, 0.f, 0.f, 0.f};
    for (int i = s0; i < s1; ++i) {
        const int s = srcidx[i];
        const float4 v = *(const float4*)(ego + (size_t)s * D_LAT + c);
        acc.x += v.x; acc.y += v.y; acc.z += v.z; acc.w += v.w;
    }
    *(float4*)(neig + (size_t)node * D_LAT + c) = acc;
}

// ---------------------------------------------------------------------------
// Kernel 3: per-layer combine, split-K register-GEMM.
// Even lane: ego @ (Wa0+Wa2); odd lane: neig @ (Wa1+Wa2); shfl-combine.
// ---------------------------------------------------------------------------
__global__ __launch_bounds__(256) void k_mlp1(
    const float* __restrict__ ego_in, const float* __restrict__ neig,
    const float* __restrict__ W1a_l, const float* __restrict__ B1a_l,
    const float* __restrict__ W1b_l, const float* __restrict__ B1b_l,
    const float* __restrict__ alpha, const int l,
    float* __restrict__ ego_out, float* __restrict__ outb)
{
    __shared__ float sWe[D_LAT * D_LAT], sWn[D_LAT * D_LAT], sWb[D_LAT * D_LAT];
    __shared__ float sBa[D_LAT], sBb[D_LAT];

    const int t = threadIdx.x;
    for (int i = t; i < D_LAT * D_LAT; i += 256) {
        const float wc = W1a_l[2 * D_LAT * D_LAT + i];   // rows 64..95 (n+e part)
        sWe[i] = W1a_l[i] + wc;
        sWn[i] = W1a_l[D_LAT * D_LAT + i] + wc;
        sWb[i] = W1b_l[i];
    }
    if (t < D_LAT) { sBa[t] = B1a_l[t]; sBb[t] = B1b_l[t]; }

    const int gtid = blockIdx.x * 256 + t;
    const size_t row = (size_t)(gtid >> 1);
    const int half = gtid & 1;
    const float4* ip = (const float4*)((half ? neig : ego_in) + row * D_LAT);
    const float* wbase = half ? sWn : sWe;
    const float al = alpha[l + 1];
    __syncthreads();

    float acc[D_LAT];
    #pragma unroll
    for (int d = 0; d < D_LAT; ++d) acc[d] = 0.f;

    // stage 1 partial: 32 features, chunks of 8 (outer loop NOT unrolled)
    #pragma unroll 1
    for (int c = 0; c < 4; ++c) {
        const float4 xa = ip[c * 2], xb = ip[c * 2 + 1];
        const float xs[8] = {xa.x, xa.y, xa.z, xa.w, xb.x, xb.y, xb.z, xb.w};
        #pragma unroll
        for (int ff = 0; ff < 8; ++ff) {
            const float xf = xs[ff];
            const float4* wr = (const float4*)(wbase + (c * 8 + ff) * D_LAT);
            #pragma unroll
            for (int dq = 0; dq < D_LAT / 4; ++dq) {
                const float4 w = wr[dq];
                acc[dq * 4 + 0] = fmaf(xf, w.x, acc[dq * 4 + 0]);
                acc[dq * 4 + 1] = fmaf(xf, w.y, acc[dq * 4 + 1]);
                acc[dq * 4 + 2] = fmaf(xf, w.z, acc[dq * 4 + 2]);
                acc[dq * 4 + 3] = fmaf(xf, w.w, acc[dq * 4 + 3]);
            }
        }
    }

    // combine ego-part + neig-part (lane pairs), bias, relu
    float h[D_LAT];
    #pragma unroll
    for (int d = 0; d < D_LAT; ++d) {
        const float s = acc[d] + __shfl_xor(acc[d], 1);
        h[d] = fmaxf(s + sBa[d], 0.f);
    }

    // stage 2: 16 output cols per lane
    float acc2[16];
    #pragma unroll
    for (int j = 0; j < 16; ++j) acc2[j] = sBb[half * 16 + j];
    #pragma unroll
    for (int dd = 0; dd < D_LAT; ++dd) {
        const float hd = h[dd];
        const float4* wr = (const float4*)(sWb + dd * D_LAT + half * 16);
        #pragma unroll
        for (int q = 0; q < 4; ++q) {
            const float4 w = wr[q];
            acc2[q * 4 + 0] = fmaf(hd, w.x, acc2[q * 4 + 0]);
            acc2[q * 4 + 1] = fmaf(hd, w.y, acc2[q * 4 + 1]);
            acc2[q * 4 + 2] = fmaf(hd, w.z, acc2[q * 4 + 2]);
            acc2[q * 4 + 3] = fmaf(hd, w.w, acc2[q * 4 + 3]);
        }
    }

    float4* eo = (float4*)(ego_out + row * D_LAT + half * 16);
    float4* oo = (float4*)(outb + row * D_LAT + half * 16);
    #pragma unroll
    for (int q = 0; q < 4; ++q) {
        const float4 prev = oo[q];
        eo[q] = make_float4(acc2[q*4], acc2[q*4+1], acc2[q*4+2], acc2[q*4+3]);
        oo[q] = make_float4(fmaf(al, acc2[q*4], prev.x),
                            fmaf(al, acc2[q*4+1], prev.y),
                            fmaf(al, acc2[q*4+2], prev.z),
                            fmaf(al, acc2[q*4+3], prev.w));
    }
}

// ---------------------------------------------------------------------------
// Per-graph top-30 (stable ties -> smaller index) + gather + relu (unchanged)
// ---------------------------------------------------------------------------
__global__ __launch_bounds__(256) void k_topk(
    const float* __restrict__ ego, const float* __restrict__ outb,
    float* __restrict__ y)
{
    __shared__ float vals[512];
    __shared__ int topidx[K_TOP];
    __shared__ float wv[4];
    __shared__ int wi[4];

    const int g = blockIdx.x, t = threadIdx.x;
    for (int i = t; i < 512; i += 256)
        vals[i] = (i < NPG) ? ego[((size_t)g * NPG + i) * D_LAT + (D_LAT - 1)]
                            : -INFINITY;
    __syncthreads();

    for (int k = 0; k < K_TOP; ++k) {
        float v = -INFINITY; int bi = 0x7fffffff;
        for (int i = t; i < NPG; i += 256) {
            const float x = vals[i];
            if (x > v || (x == v && i < bi)) { v = x; bi = i; }
        }
        for (int off = 32; off > 0; off >>= 1) {
            const float ov = __shfl_down(v, off);
            const int   oi = __shfl_down(bi, off);
            if (ov > v || (ov == v && oi < bi)) { v = ov; bi = oi; }
        }
        if ((t & 63) == 0) { wv[t >> 6] = v; wi[t >> 6] = bi; }
        __syncthreads();
        if (t == 0) {
            for (int w = 1; w < 4; ++w)
                if (wv[w] > v || (wv[w] == v && wi[w] < bi)) { v = wv[w]; bi = wi[w]; }
            topidx[k] = bi;
            vals[bi] = -INFINITY;
        }
        __syncthreads();
    }

    for (int j = t; j < K_TOP * D_LAT; j += 256) {
        const int kk = j >> 5, d = j & 31;
        const size_t node = (size_t)g * NPG + topidx[kk];
        y[(size_t)g * (K_TOP * D_LAT) + j] = fmaxf(outb[node * D_LAT + d], 0.f);
    }
}

// ---------------------------------------------------------------------------
extern "C" void kernel_launch(void* const* d_in, const int* in_sizes, int n_in,
                              void* d_out, int out_size, void* d_ws, size_t ws_size,
                              hipStream_t stream)
{
    const float* X    = (const float*)d_in[0];
    const float* alpha= (const float*)d_in[1];
    const float* w0a  = (const float*)d_in[2];
    const float* b0a  = (const float*)d_in[3];
    const float* w0b  = (const float*)d_in[4];
    const float* b0b  = (const float*)d_in[5];
    const float* W1a  = (const float*)d_in[6];
    const float* B1a  = (const float*)d_in[7];
    const float* W1b  = (const float*)d_in[8];
    const float* B1b  = (const float*)d_in[9];
    const int* esrc   = (const int*)d_in[10];
    const int* edst   = (const int*)d_in[11];
    float* y = (float*)d_out;

    float* ego    = (float*)d_ws;
    float* outb   = ego  + (size_t)N_NODES * D_LAT;
    float* neig   = outb + (size_t)N_NODES * D_LAT;
    int*   packed = (int*)neig;                              // alias: dead before 1st gather
    int*   off    = (int*)(neig + (size_t)N_NODES * D_LAT);  // N+1
    int*   srcidx = off + (N_NODES + 1);                     // E
    int*   ghist  = srcidx + E_EDGES;                        // NB
    int*   gbase  = ghist + NB;                              // NB+1
    int*   gcursor= gbase + (NB + 1);                        // NB

    hipMemsetAsync(ghist, 0, NB * sizeof(int), stream);
    k_bcount  <<<CBLOCKS, 256, 0, stream>>>(edst, ghist);
    k_bscan   <<<1, 1024, 0, stream>>>(ghist, gbase, gcursor);
    k_bscatter<<<CBLOCKS, 256, 0, stream>>>(esrc, edst, gcursor, packed);
    k_bcsr    <<<NB, 256, 0, stream>>>(gbase, packed, off, srcidx);

    k_mlp0<<<N_NODES * 2 / 256, 256, 0, stream>>>(X, w0a, b0a, w0b, b0b, alpha, ego, outb);

    for (int l = 0; l < L_LAYERS; ++l) {
        k_gather<<<N_NODES / 32, 256, 0, stream>>>(ego, off, srcidx, neig);
        k_mlp1<<<N_NODES * 2 / 256, 256, 0, stream>>>(
            ego, neig, W1a + (size_t)l * 96 * 32, B1a + (size_t)l * 32,
            W1b + (size_t)l * 32 * 32, B1b + (size_t)l * 32, alpha, l, ego, outb);
    }

    k_topk<<<B_G, 256, 0, stream>>>(ego, outb, y);
}

// Round 7
// 430.844 us; speedup vs baseline: 24.8180x; 1.0892x over previous
//
#include <hip/hip_runtime.h>
#include <math.h>

#define N_NODES 128000
#define B_G 256
#define NPG 500
#define F_IN 128
#define D_LAT 32
#define K_TOP 30
#define L_LAYERS 3
#define E_EDGES 2048000

#define BSH 7                      // bucket = dst >> 7
#define NB (N_NODES >> BSH)        // 1000 buckets x 128 nodes
#define CHUNK 8192
#define CBLOCKS (E_EDGES / CHUNK)  // 250

// ---------------------------------------------------------------------------
// Fold the concat weights once: We = Wa0+Wa2, Wn = Wa1+Wa2 (per layer).
// Enables wave-uniform (scalar-path) weight reads in k_layer.
// ---------------------------------------------------------------------------
__global__ __launch_bounds__(256) void k_foldw(
    const float* __restrict__ W1a, float* __restrict__ wfold)
{
    const int l = blockIdx.x, t = threadIdx.x;
    const float* base = W1a + (size_t)l * 3 * D_LAT * D_LAT;
    float* o = wfold + (size_t)l * 2 * D_LAT * D_LAT;
    for (int i = t; i < D_LAT * D_LAT; i += 256) {
        const float wc = base[2 * D_LAT * D_LAT + i];
        o[i] = base[i] + wc;                       // We
        o[D_LAT * D_LAT + i] = base[D_LAT * D_LAT + i] + wc;  // Wn
    }
}

// ---------------------------------------------------------------------------
// Kernel 1: ego = relu(X @ w0a + b0a) @ w0b + b0b ;  out = alpha[0] * ego
// Thread = row. Weights read at wave-uniform addresses -> scalar (SGPR) path.
// No LDS, no shuffles.
// ---------------------------------------------------------------------------
__global__ __launch_bounds__(256) void k_mlp0(
    const float* __restrict__ X, const float* __restrict__ w0a,
    const float* __restrict__ b0a, const float* __restrict__ w0b,
    const float* __restrict__ b0b, const float* __restrict__ alpha,
    float* __restrict__ ego, float* __restrict__ outb)
{
    const size_t row = (size_t)blockIdx.x * 256 + threadIdx.x;
    const float4* xp = (const float4*)(X + row * F_IN);
    const float a0 = alpha[0];

    float acc[D_LAT];
    #pragma unroll
    for (int j = 0; j < D_LAT; ++j) acc[j] = b0a[j];

    // stage 1: 128 -> 32, chunks of 16 features (outer loop NOT unrolled)
    #pragma unroll 1
    for (int c = 0; c < F_IN / 16; ++c) {
        const float4 x0 = xp[c * 4 + 0], x1 = xp[c * 4 + 1];
        const float4 x2 = xp[c * 4 + 2], x3 = xp[c * 4 + 3];
        const float xs[16] = {x0.x, x0.y, x0.z, x0.w, x1.x, x1.y, x1.z, x1.w,
                              x2.x, x2.y, x2.z, x2.w, x3.x, x3.y, x3.z, x3.w};
        #pragma unroll
        for (int ff = 0; ff < 16; ++ff) {
            const float xf = xs[ff];
            const float* wr = w0a + (c * 16 + ff) * D_LAT;   // uniform addr
            #pragma unroll
            for (int j = 0; j < D_LAT; ++j)
                acc[j] = fmaf(xf, wr[j], acc[j]);
        }
    }

    // relu (in place)
    #pragma unroll
    for (int j = 0; j < D_LAT; ++j) acc[j] = fmaxf(acc[j], 0.f);

    // stage 2: 32 -> 32, chunks of 8
    float acc2[D_LAT];
    #pragma unroll
    for (int j = 0; j < D_LAT; ++j) acc2[j] = b0b[j];
    #pragma unroll 1
    for (int c = 0; c < D_LAT / 8; ++c) {
        #pragma unroll
        for (int kk = 0; kk < 8; ++kk) {
            const float h = acc[c * 8 + kk];
            const float* wr = w0b + (c * 8 + kk) * D_LAT;    // uniform addr
            #pragma unroll
            for (int j = 0; j < D_LAT; ++j)
                acc2[j] = fmaf(h, wr[j], acc2[j]);
        }
    }

    float4* eo = (float4*)(ego + row * D_LAT);
    float4* oo = (float4*)(outb + row * D_LAT);
    #pragma unroll
    for (int q = 0; q < D_LAT / 4; ++q) {
        eo[q] = make_float4(acc2[q*4], acc2[q*4+1], acc2[q*4+2], acc2[q*4+3]);
        oo[q] = make_float4(a0*acc2[q*4], a0*acc2[q*4+1],
                            a0*acc2[q*4+2], a0*acc2[q*4+3]);
    }
}

// ---------------------------------------------------------------------------
// Radix CSR build (unchanged)
// ---------------------------------------------------------------------------
__global__ __launch_bounds__(256) void k_bcount(
    const int* __restrict__ edst, int* __restrict__ ghist)
{
    __shared__ int cnt[NB];
    const int t = threadIdx.x;
    for (int i = t; i < NB; i += 256) cnt[i] = 0;
    __syncthreads();
    const int ebase = blockIdx.x * CHUNK;
    for (int i = 0; i < CHUNK / 256; ++i)
        atomicAdd(&cnt[edst[ebase + i * 256 + t] >> BSH], 1);
    __syncthreads();
    for (int i = t; i < NB; i += 256)
        if (cnt[i]) atomicAdd(&ghist[i], cnt[i]);
}

__global__ __launch_bounds__(1024) void k_bscan(
    const int* __restrict__ ghist, int* __restrict__ gbase,
    int* __restrict__ gcursor)
{
    __shared__ int buf[2][1024];
    const int t = threadIdx.x;
    const int v = (t < NB) ? ghist[t] : 0;
    buf[0][t] = v;
    __syncthreads();
    int cur = 0;
    for (int o = 1; o < 1024; o <<= 1) {
        int x = buf[cur][t];
        if (t >= o) x += buf[cur][t - o];
        buf[cur ^ 1][t] = x;
        cur ^= 1;
        __syncthreads();
    }
    if (t < NB) { const int e = buf[cur][t] - v; gbase[t] = e; gcursor[t] = e; }
    if (t == 0) gbase[NB] = E_EDGES;
}

__global__ __launch_bounds__(256) void k_bscatter(
    const int* __restrict__ esrc, const int* __restrict__ edst,
    int* __restrict__ gcursor, int* __restrict__ packed)
{
    __shared__ int cnt[NB];
    __shared__ int sbase[NB];
    const int t = threadIdx.x;
    for (int i = t; i < NB; i += 256) cnt[i] = 0;
    __syncthreads();
    const int ebase = blockIdx.x * CHUNK;
    for (int i = 0; i < CHUNK / 256; ++i)
        atomicAdd(&cnt[edst[ebase + i * 256 + t] >> BSH], 1);
    __syncthreads();
    for (int i = t; i < NB; i += 256) {
        const int c = cnt[i];
        sbase[i] = c ? atomicAdd(&gcursor[i], c) : 0;
        cnt[i] = 0;
    }
    __syncthreads();
    for (int i = 0; i < CHUNK / 256; ++i) {
        const int e = ebase + i * 256 + t;
        const int d = edst[e], s = esrc[e];
        const int b = d >> BSH;
        const int r = atomicAdd(&cnt[b], 1);
        packed[sbase[b] + r] = (s << BSH) | (d & ((1 << BSH) - 1));
    }
}

__global__ __launch_bounds__(256) void k_bcsr(
    const int* __restrict__ gbase, const int* __restrict__ packed,
    int* __restrict__ off, int* __restrict__ srcidx)
{
    __shared__ int cnt[128];
    __shared__ int scn[128];
    __shared__ int sbuf[4096];
    const int b = blockIdx.x, t = threadIdx.x;
    const int s0 = gbase[b], s1 = gbase[b + 1], m = s1 - s0;

    if (t < 128) cnt[t] = 0;
    __syncthreads();
    for (int i = t; i < m; i += 256)
        atomicAdd(&cnt[packed[s0 + i] & 127], 1);
    __syncthreads();
    if (t == 0) {
        int a = 0;
        for (int k = 0; k < 128; ++k) { scn[k] = a; a += cnt[k]; }
    }
    __syncthreads();
    if (t < 128) { off[(b << BSH) + t] = s0 + scn[t]; cnt[t] = 0; }
    if (b == 0 && t == 0) off[N_NODES] = E_EDGES;
    __syncthreads();
    for (int i = t; i < m; i += 256) {
        const int p = packed[s0 + i];
        const int dl = p & 127;
        const int r = atomicAdd(&cnt[dl], 1);
        sbuf[scn[dl] + r] = p >> BSH;
    }
    __syncthreads();
    for (int i = t; i < m; i += 256) srcidx[s0 + i] = sbuf[i];
}

// ---------------------------------------------------------------------------
// Fused layer: neig = segment-sum of in[src] (register gather), then
// ego' = relu([in|neig|in+neig] @ W1a + B1a) @ W1b + B1b  (concat folded),
// out += alpha[l+1] * ego'. Thread = node. in != out (ping-pong) -> race-free.
// Weights wave-uniform -> scalar path. No LDS.
// ---------------------------------------------------------------------------
__global__ __launch_bounds__(256) void k_layer(
    const float* __restrict__ in, const int* __restrict__ off,
    const int* __restrict__ srcidx, const float* __restrict__ wfold_l,
    const float* __restrict__ W1b_l, const float* __restrict__ B1a_l,
    const float* __restrict__ B1b_l, const float* __restrict__ alpha,
    const int l, float* __restrict__ out, float* __restrict__ outb)
{
    const size_t n = (size_t)blockIdx.x * 256 + threadIdx.x;
    const int s0 = off[n], s1 = off[n + 1];
    const float al = alpha[l + 1];

    // register gather: neig = sum of neighbor rows
    float4 ng4[D_LAT / 4];
    #pragma unroll
    for (int q = 0; q < D_LAT / 4; ++q) ng4[q] = make_float4(0.f, 0.f, 0.f, 0.f);
    int s = (s0 < s1) ? srcidx[s0] : 0;
    for (int i = s0; i < s1; ++i) {
        const int snext = (i + 1 < s1) ? srcidx[i + 1] : 0;
        const float4* vp = (const float4*)(in + (size_t)s * D_LAT);
        #pragma unroll
        for (int q = 0; q < D_LAT / 4; ++q) {
            const float4 v = vp[q];
            ng4[q].x += v.x; ng4[q].y += v.y; ng4[q].z += v.z; ng4[q].w += v.w;
        }
        s = snext;
    }
    float ngs[D_LAT];
    #pragma unroll
    for (int q = 0; q < D_LAT / 4; ++q) {
        ngs[q*4] = ng4[q].x; ngs[q*4+1] = ng4[q].y;
        ngs[q*4+2] = ng4[q].z; ngs[q*4+3] = ng4[q].w;
    }

    // own row
    float eg[D_LAT];
    {
        const float4* ep = (const float4*)(in + n * D_LAT);
        #pragma unroll
        for (int q = 0; q < D_LAT / 4; ++q) {
            const float4 v = ep[q];
            eg[q*4] = v.x; eg[q*4+1] = v.y; eg[q*4+2] = v.z; eg[q*4+3] = v.w;
        }
    }

    // stage 1: ego @ We + neig @ Wn + B1a, chunks of 8 k's
    float acc[D_LAT];
    #pragma unroll
    for (int j = 0; j < D_LAT; ++j) acc[j] = B1a_l[j];
    #pragma unroll 1
    for (int c = 0; c < D_LAT / 8; ++c) {
        #pragma unroll
        for (int kk = 0; kk < 8; ++kk) {
            const int k = c * 8 + kk;
            const float fe = eg[k], fn = ngs[k];
            const float* we = wfold_l + k * D_LAT;                    // uniform
            const float* wn = wfold_l + D_LAT * D_LAT + k * D_LAT;    // uniform
            #pragma unroll
            for (int j = 0; j < D_LAT; ++j)
                acc[j] = fmaf(fe, we[j], fmaf(fn, wn[j], acc[j]));
        }
    }
    #pragma unroll
    for (int j = 0; j < D_LAT; ++j) acc[j] = fmaxf(acc[j], 0.f);

    // stage 2
    float acc2[D_LAT];
    #pragma unroll
    for (int j = 0; j < D_LAT; ++j) acc2[j] = B1b_l[j];
    #pragma unroll 1
    for (int c = 0; c < D_LAT / 8; ++c) {
        #pragma unroll
        for (int kk = 0; kk < 8; ++kk) {
            const float h = acc[c * 8 + kk];
            const float* wr = W1b_l + (c * 8 + kk) * D_LAT;           // uniform
            #pragma unroll
            for (int j = 0; j < D_LAT; ++j)
                acc2[j] = fmaf(h, wr[j], acc2[j]);
        }
    }

    float4* eo = (float4*)(out + n * D_LAT);
    float4* oo = (float4*)(outb + n * D_LAT);
    #pragma unroll
    for (int q = 0; q < D_LAT / 4; ++q) {
        const float4 prev = oo[q];
        eo[q] = make_float4(acc2[q*4], acc2[q*4+1], acc2[q*4+2], acc2[q*4+3]);
        oo[q] = make_float4(fmaf(al, acc2[q*4], prev.x),
                            fmaf(al, acc2[q*4+1], prev.y),
                            fmaf(al, acc2[q*4+2], prev.z),
                            fmaf(al, acc2[q*4+3], prev.w));
    }
}

// ---------------------------------------------------------------------------
// Per-graph top-30 (stable ties -> smaller index) + gather + relu (unchanged)
// ---------------------------------------------------------------------------
__global__ __launch_bounds__(256) void k_topk(
    const float* __restrict__ ego, const float* __restrict__ outb,
    float* __restrict__ y)
{
    __shared__ float vals[512];
    __shared__ int topidx[K_TOP];
    __shared__ float wv[4];
    __shared__ int wi[4];

    const int g = blockIdx.x, t = threadIdx.x;
    for (int i = t; i < 512; i += 256)
        vals[i] = (i < NPG) ? ego[((size_t)g * NPG + i) * D_LAT + (D_LAT - 1)]
                            : -INFINITY;
    __syncthreads();

    for (int k = 0; k < K_TOP; ++k) {
        float v = -INFINITY; int bi = 0x7fffffff;
        for (int i = t; i < NPG; i += 256) {
            const float x = vals[i];
            if (x > v || (x == v && i < bi)) { v = x; bi = i; }
        }
        for (int off = 32; off > 0; off >>= 1) {
            const float ov = __shfl_down(v, off);
            const int   oi = __shfl_down(bi, off);
            if (ov > v || (ov == v && oi < bi)) { v = ov; bi = oi; }
        }
        if ((t & 63) == 0) { wv[t >> 6] = v; wi[t >> 6] = bi; }
        __syncthreads();
        if (t == 0) {
            for (int w = 1; w < 4; ++w)
                if (wv[w] > v || (wv[w] == v && wi[w] < bi)) { v = wv[w]; bi = wi[w]; }
            topidx[k] = bi;
            vals[bi] = -INFINITY;
        }
        __syncthreads();
    }

    for (int j = t; j < K_TOP * D_LAT; j += 256) {
        const int kk = j >> 5, d = j & 31;
        const size_t node = (size_t)g * NPG + topidx[kk];
        y[(size_t)g * (K_TOP * D_LAT) + j] = fmaxf(outb[node * D_LAT + d], 0.f);
    }
}

// ---------------------------------------------------------------------------
extern "C" void kernel_launch(void* const* d_in, const int* in_sizes, int n_in,
                              void* d_out, int out_size, void* d_ws, size_t ws_size,
                              hipStream_t stream)
{
    const float* X    = (const float*)d_in[0];
    const float* alpha= (const float*)d_in[1];
    const float* w0a  = (const float*)d_in[2];
    const float* b0a  = (const float*)d_in[3];
    const float* w0b  = (const float*)d_in[4];
    const float* b0b  = (const float*)d_in[5];
    const float* W1a  = (const float*)d_in[6];
    const float* B1a  = (const float*)d_in[7];
    const float* W1b  = (const float*)d_in[8];
    const float* B1b  = (const float*)d_in[9];
    const int* esrc   = (const int*)d_in[10];
    const int* edst   = (const int*)d_in[11];
    float* y = (float*)d_out;

    float* egoA   = (float*)d_ws;
    float* outb   = egoA + (size_t)N_NODES * D_LAT;
    float* egoB   = outb + (size_t)N_NODES * D_LAT;          // was "neig"
    int*   packed = (int*)egoB;                              // alias: dead before layer 0
    int*   off    = (int*)(egoB + (size_t)N_NODES * D_LAT);  // N+1
    int*   srcidx = off + (N_NODES + 1);                     // E
    int*   ghist  = srcidx + E_EDGES;                        // NB
    int*   gbase  = ghist + NB;                              // NB+1
    int*   gcursor= gbase + (NB + 1);                        // NB
    float* wfold  = (float*)(gcursor + NB);                  // 3 * 2048

    k_foldw<<<L_LAYERS, 256, 0, stream>>>(W1a, wfold);

    hipMemsetAsync(ghist, 0, NB * sizeof(int), stream);
    k_bcount  <<<CBLOCKS, 256, 0, stream>>>(edst, ghist);
    k_bscan   <<<1, 1024, 0, stream>>>(ghist, gbase, gcursor);
    k_bscatter<<<CBLOCKS, 256, 0, stream>>>(esrc, edst, gcursor, packed);
    k_bcsr    <<<NB, 256, 0, stream>>>(gbase, packed, off, srcidx);

    k_mlp0<<<N_NODES / 256, 256, 0, stream>>>(X, w0a, b0a, w0b, b0b, alpha, egoA, outb);

    float* cur = egoA;
    float* nxt = egoB;
    for (int l = 0; l < L_LAYERS; ++l) {
        k_layer<<<N_NODES / 256, 256, 0, stream>>>(
            cur, off, srcidx, wfold + (size_t)l * 2 * D_LAT * D_LAT,
            W1b + (size_t)l * D_LAT * D_LAT, B1a + (size_t)l * D_LAT,
            B1b + (size_t)l * D_LAT, alpha, l, nxt, outb);
        float* tmp = cur; cur = nxt; nxt = tmp;
    }

    // after 3 layers, final ego is in `cur` (== egoB)
    k_topk<<<B_G, 256, 0, stream>>>(cur, outb, y);
}